// Round 4
// baseline (1142.501 us; speedup 1.0000x reference)
//
#include <hip/hip_runtime.h>

// EquivLayerNorm — 2-kernel streaming plan for MI355X.
//
// Math (exact algebraic collapse of the reference):
//   gmean = segmean_n( mean_j s[n,j] )
//   gvar  = max( segmean_n( mean_j s^2 ) - gmean^2 , EPS )
//   sout  = (s - gmean) / gvar * w + b          (divide by var, per source)
//   gvm   = max( segmean_n( sum_{axis,d} v^2 ) / 64 , EPS )
//   vout  = v / gvm
//
// K1 (stats): one block per graph (batch is sorted -> contiguous ranges found
//   by a tid<2 binary search). Streams s+v once (640 MB), writes per-graph
//   {gmean, 1/gvar, 1/gvm} float4 into ws. ~105 us at ~6 TB/s.
// K2 (normalize): pure grid-stride streaming, no barriers. Reads s+v again
//   (640 MB) + writes 640 MB. Iterates chunks in REVERSE address order so the
//   tail stripes of K1's reads (still resident in the 256 MB Infinity Cache)
//   are consumed before they get evicted — free, fully coalesced.
// Previous fused single-kernel relied on phase-2 L3 hits; churn analysis
// (256 blocks x 1.25 MB read+write = 320 MB > 256 MB L3) says that plan is
// structurally marginal, matching the observed ~350-390 us.

#define K1_THREADS 256
#define K1_GRID    1024
#define K2_THREADS 256
#define K2_SBLK    1024   // blocks for the s-part  (work ratio s:v = 2:3)
#define K2_VBLK    1536   // blocks for the v-part
#define K2_UNROLL  8
#define EPS 1e-6f

typedef float vfloat4 __attribute__((ext_vector_type(4)));

__device__ __forceinline__ int lower_bound_i(const int* __restrict__ a, int n, int val) {
    int lo = 0, hi = n;
    while (lo < hi) {
        int mid = (lo + hi) >> 1;
        if (a[mid] < val) lo = mid + 1; else hi = mid;
    }
    return lo;
}

__device__ __forceinline__ void nt_store4(float4* p, float4 x) {
    vfloat4 r; r.x = x.x; r.y = x.y; r.z = x.z; r.w = x.w;
    __builtin_nontemporal_store(r, reinterpret_cast<vfloat4*>(p));
}

// ---------------- K1: per-graph stats ----------------
__global__ __launch_bounds__(K1_THREADS) void eln_stats(
    const float* __restrict__ s, const float* __restrict__ v,
    const int* __restrict__ batch, float4* __restrict__ stats,
    int N, int statCap)
{
    __shared__ int sh_se[2];
    __shared__ float red[K1_THREADS / 64][3];

    const int Beff = batch[N - 1] + 1;
    const int tid  = threadIdx.x;
    const int lane = tid & 63;
    const int wid  = tid >> 6;

    const float4* s4 = reinterpret_cast<const float4*>(s);
    const float4* v4 = reinterpret_cast<const float4*>(v);

    for (int g = blockIdx.x; g < Beff && g < statCap; g += gridDim.x) {
        if (tid < 2) sh_se[tid] = lower_bound_i(batch, N, g + tid);
        __syncthreads();
        const int start = sh_se[0], end = sh_se[1];

        float ss = 0.f, ss2 = 0.f, sv2 = 0.f;
        const int s_hi = end * 32;   // float4 indices (32 float4 per s-row)
        const int v_hi = end * 48;   // 48 float4 per v-row
        #pragma unroll 8
        for (int i = start * 32 + tid; i < s_hi; i += K1_THREADS) {
            float4 x = s4[i];
            ss  += (x.x + x.y) + (x.z + x.w);
            ss2 += x.x * x.x + x.y * x.y + x.z * x.z + x.w * x.w;
        }
        #pragma unroll 8
        for (int i = start * 48 + tid; i < v_hi; i += K1_THREADS) {
            float4 x = v4[i];
            sv2 += x.x * x.x + x.y * x.y + x.z * x.z + x.w * x.w;
        }
        #pragma unroll
        for (int o = 32; o > 0; o >>= 1) {
            ss  += __shfl_down(ss,  o, 64);
            ss2 += __shfl_down(ss2, o, 64);
            sv2 += __shfl_down(sv2, o, 64);
        }
        if (lane == 0) { red[wid][0] = ss; red[wid][1] = ss2; red[wid][2] = sv2; }
        __syncthreads();
        if (tid == 0) {
            float ts = 0.f, ts2 = 0.f, tv2 = 0.f;
            #pragma unroll
            for (int w = 0; w < K1_THREADS / 64; ++w) {
                ts += red[w][0]; ts2 += red[w][1]; tv2 += red[w][2];
            }
            const float fc    = fmaxf((float)(end - start), 1.0f);
            const float invns = 1.0f / (128.0f * fc);
            const float gmean = ts * invns;
            const float gvar  = fmaxf(ts2 * invns - gmean * gmean, EPS);
            const float gvm   = fmaxf(tv2 / (64.0f * fc), EPS);
            stats[g] = make_float4(gmean, 1.0f / gvar, 1.0f / gvm, 0.0f);
        }
        __syncthreads();   // protect sh_se/red reuse on next grid-stride iter
    }
}

// ---------------- K2: streaming normalize (reverse order) ----------------
__global__ __launch_bounds__(K2_THREADS) void eln_norm(
    const float* __restrict__ s, const float* __restrict__ v,
    const float* __restrict__ wgt, const float* __restrict__ bia,
    const int* __restrict__ batch, const float4* __restrict__ stats,
    float* __restrict__ souts, float* __restrict__ vouts, int N)
{
    const int tid = threadIdx.x;
    const int CH  = K2_THREADS * K2_UNROLL;   // float4 per block-chunk

    if (blockIdx.x < K2_SBLK) {
        // ---- s part: sout = (s - gmean)*ivar*w + b ----
        const float4* s4  = reinterpret_cast<const float4*>(s);
        float4*       so4 = reinterpret_cast<float4*>(souts);
        const float4* w4t = reinterpret_cast<const float4*>(wgt);
        const float4* b4t = reinterpret_cast<const float4*>(bia);
        const int total = N * 32;             // 16e6 float4, fits int
        const int nch   = (total + CH - 1) / CH;
        for (int c = blockIdx.x; c < nch; c += K2_SBLK) {
            const int base = (nch - 1 - c) * CH + tid;   // reversed chunk
            #pragma unroll
            for (int u = 0; u < K2_UNROLL; ++u) {
                const int i = base + u * K2_THREADS;
                if (i < total) {
                    float4 x = s4[i];
                    const int node = i >> 5;
                    const int col  = i & 31;
                    const float4 st = stats[batch[node]];
                    const float4 w  = w4t[col];
                    const float4 b  = b4t[col];
                    float4 o;
                    o.x = (x.x - st.x) * st.y * w.x + b.x;
                    o.y = (x.y - st.x) * st.y * w.y + b.y;
                    o.z = (x.z - st.x) * st.y * w.z + b.z;
                    o.w = (x.w - st.x) * st.y * w.w + b.w;
                    nt_store4(&so4[i], o);
                }
            }
        }
    } else {
        // ---- v part: vout = v * ivm ----
        const float4* v4  = reinterpret_cast<const float4*>(v);
        float4*       vo4 = reinterpret_cast<float4*>(vouts);
        const int total = N * 48;             // 24e6 float4, fits int
        const int nch   = (total + CH - 1) / CH;
        for (int c = blockIdx.x - K2_SBLK; c < nch; c += K2_VBLK) {
            const int base = (nch - 1 - c) * CH + tid;   // reversed chunk
            #pragma unroll
            for (int u = 0; u < K2_UNROLL; ++u) {
                const int i = base + u * K2_THREADS;
                if (i < total) {
                    float4 x = v4[i];
                    const int node = i / 48;             // 32-bit magic-mul
                    const float ivm = stats[batch[node]].z;
                    float4 o;
                    o.x = x.x * ivm; o.y = x.y * ivm;
                    o.z = x.z * ivm; o.w = x.w * ivm;
                    nt_store4(&vo4[i], o);
                }
            }
        }
    }
}

extern "C" void kernel_launch(void* const* d_in, const int* in_sizes, int n_in,
                              void* d_out, int out_size, void* d_ws, size_t ws_size,
                              hipStream_t stream) {
    const float* s   = (const float*)d_in[0];
    const float* v   = (const float*)d_in[1];
    const float* wgt = (const float*)d_in[2];
    const float* bia = (const float*)d_in[3];
    const int*   bat = (const int*)d_in[4];
    const int N = in_sizes[4];

    float* souts = (float*)d_out;
    float* vouts = souts + (size_t)N * 128;

    float4* stats = (float4*)d_ws;                      // ws is ~1.9 GB; need Beff*16 B
    int statCap = (int)(ws_size / sizeof(float4));
    if (statCap > (1 << 24)) statCap = 1 << 24;

    eln_stats<<<K1_GRID, K1_THREADS, 0, stream>>>(s, v, bat, stats, N, statCap);
    eln_norm<<<K2_SBLK + K2_VBLK, K2_THREADS, 0, stream>>>(
        s, v, wgt, bia, bat, stats, souts, vouts, N);
}